// Round 1
// baseline (157.718 us; speedup 1.0000x reference)
//
#include <hip/hip_runtime.h>

// Problem constants (fixed by setup_inputs).
constexpr int B_   = 16;
constexpr int C_   = 3;
constexpr int HW_  = 512 * 512;          // 262144 pixels per image
constexpr int THREADS = 256;
constexpr int BLOCKS_PER_IMG = 128;
constexpr int NBLOCKS = B_ * BLOCKS_PER_IMG;             // 2048
constexpr int F4_PER_BLOCK = HW_ / 4 / BLOCKS_PER_IMG;   // 512 float4 per block
constexpr int ITERS = F4_PER_BLOCK / THREADS;            // 2 -> 8 pixels/thread
constexpr int REC = 8;   // floats per block record (2 x float4)

// Record layout per block (8 floats):
//  [0] ce sum (float)
//  [1] cnt1 | cnt2<<16        (bit-cast u32; cnt0 derived at the end)
//  [2] tps0 | tps1<<16
//  [3] tps2 | itr0<<16
//  [4] itr1 | itr2<<16
//  [5..7] pad
// Per-block packed fields are <= 2048 (pixels/block) < 2^16: no overflow.
//
// Arrival counter (u32) lives at ws[CNT_OFF_FLOATS] (byte offset 64 KB),
// zeroed by a 4-byte hipMemsetAsync before the kernel. Last-arriving block
// performs the final reduction (identical FP order to the old dice_ce_final).
constexpr size_t CNT_OFF_FLOATS = (size_t)NBLOCKS * REC;  // 16384 floats

__global__ __launch_bounds__(THREADS) void dice_ce_fused(
    const float* __restrict__ pred, const int* __restrict__ tgt,
    float* __restrict__ ws, float* __restrict__ out) {
  const int b = blockIdx.x / BLOCKS_PER_IMG;
  const int j = blockIdx.x % BLOCKS_PER_IMG;
  const int t = threadIdx.x;

  const float4* p0 = (const float4*)(pred + (size_t)b * C_ * HW_);
  const float4* p1 = (const float4*)(pred + (size_t)b * C_ * HW_ + HW_);
  const float4* p2 = (const float4*)(pred + (size_t)b * C_ * HW_ + 2 * HW_);
  const int4*   tg = (const int4*)(tgt + (size_t)b * HW_);

  // Issue ALL loads up front -> 8 outstanding vmem ops per wave.
  float4 A0[ITERS], A1[ITERS], A2[ITERS];
  int4   T[ITERS];
#pragma unroll
  for (int i = 0; i < ITERS; ++i) {
    const int idx = j * F4_PER_BLOCK + i * THREADS + t;
    A0[i] = p0[idx];
    A1[i] = p1[idx];
    A2[i] = p2[idx];
    T[i]  = tg[idx];
  }

  float ce = 0.f;
  int pkA = 0, pkB = 0, pkC = 0, pkD = 0;

#pragma unroll
  for (int i = 0; i < ITERS; ++i) {
    float x0s[4] = {A0[i].x, A0[i].y, A0[i].z, A0[i].w};
    float x1s[4] = {A1[i].x, A1[i].y, A1[i].z, A1[i].w};
    float x2s[4] = {A2[i].x, A2[i].y, A2[i].z, A2[i].w};
    int   tvs[4] = {T[i].x, T[i].y, T[i].z, T[i].w};
#pragma unroll
    for (int k = 0; k < 4; ++k) {
      float x0 = x0s[k], x1 = x1s[k], x2 = x2s[k];
      int tv = tvs[k];
      float m  = fmaxf(x0, fmaxf(x1, x2));
      float e0 = __expf(x0 - m), e1 = __expf(x1 - m), e2 = __expf(x2 - m);
      float s  = e0 + e1 + e2;
      float ls = __logf(s);
      float xt = (tv == 0) ? x0 : ((tv == 1) ? x1 : x2);
      ce += (m + ls) - xt;  // -= logp[target]
      // trunc(softmax prob) == 1 iff e_i carries the whole f32 sum (prob
      // rounds to exactly 1.0). Needs logit gap > ~16.6; never for N(0,1).
      int t0 = (e0 >= s) ? 1 : 0;
      int t1 = (e1 >= s) ? 1 : 0;
      int t2 = (e2 >= s) ? 1 : 0;
      pkA += ((tv == 1) ? 1 : 0) + ((tv == 2) ? (1 << 16) : 0);
      pkB += t0 + (t1 << 16);
      pkC += t2 + (((tv == 0) ? t0 : 0) << 16);
      pkD += ((tv == 1) ? t1 : 0) + (((tv == 2) ? t2 : 0) << 16);
    }
  }

  // Block reduction of 5 channels: wave shuffle then cross-wave LDS.
  int pks[4] = {pkA, pkB, pkC, pkD};
#pragma unroll
  for (int off = 32; off > 0; off >>= 1) {
    ce += __shfl_down(ce, off, 64);
#pragma unroll
    for (int k = 0; k < 4; ++k) pks[k] += __shfl_down(pks[k], off, 64);
  }

  __shared__ float ceR[THREADS / 64];
  __shared__ int   pkR[THREADS / 64][4];
  __shared__ int   lastFlag;
  __shared__ float ceS[B_];
  __shared__ float coefS[B_];
  const int wave = t >> 6, lane = t & 63;
  if (lane == 0) {
    ceR[wave] = ce;
#pragma unroll
    for (int k = 0; k < 4; ++k) pkR[wave][k] = pks[k];
  }
  __syncthreads();
  if (t == 0) {
#pragma unroll
    for (int w = 1; w < THREADS / 64; ++w) {
      ce += ceR[w];
#pragma unroll
      for (int k = 0; k < 4; ++k) pks[k] += pkR[w][k];
    }
    float4* rec = (float4*)(ws + (size_t)blockIdx.x * REC);
    rec[0] = make_float4(ce, __int_as_float(pks[0]), __int_as_float(pks[1]),
                         __int_as_float(pks[2]));
    rec[1] = make_float4(__int_as_float(pks[3]), 0.f, 0.f, 0.f);
    // Release: make the record visible device-wide, then signal arrival.
    __threadfence();
    unsigned int old =
        atomicAdd((unsigned int*)(ws + CNT_OFF_FLOATS), 1u);
    lastFlag = (old == (unsigned int)(NBLOCKS - 1)) ? 1 : 0;
  }
  __syncthreads();
  if (lastFlag == 0) return;

  // ---- Tail: last-arriving block does the final reduction. ----
  // Acquire: invalidate caches so other blocks' records are visible.
  __threadfence();

  // 4 waves x 4 image-groups == the old 16-wave final kernel; per-image
  // arithmetic order is IDENTICAL (same lane->record pairing, same
  // shuffle tree, same image-order final sum) -> bitwise-same result.
#pragma unroll
  for (int g = 0; g < 4; ++g) {
    const int img = g * 4 + wave;
    float ce2 = 0.f;
    float cnt1 = 0.f, cnt2 = 0.f;
    float tps0 = 0.f, tps1 = 0.f, tps2 = 0.f;
    float itr0 = 0.f, itr1 = 0.f, itr2 = 0.f;
#pragma unroll
    for (int r = 0; r < 2; ++r) {
      const int idx = img * BLOCKS_PER_IMG + r * 64 + lane;
      const float4* rec = (const float4*)(ws + (size_t)idx * REC);
      float4 r0 = rec[0], r1 = rec[1];
      ce2 += r0.x;
      int pA = __float_as_int(r0.y), pB = __float_as_int(r0.z);
      int pC = __float_as_int(r0.w), pD = __float_as_int(r1.x);
      cnt1 += (float)(pA & 0xffff); cnt2 += (float)(pA >> 16);
      tps0 += (float)(pB & 0xffff); tps1 += (float)(pB >> 16);
      tps2 += (float)(pC & 0xffff); itr0 += (float)(pC >> 16);
      itr1 += (float)(pD & 0xffff); itr2 += (float)(pD >> 16);
    }
    float v[9] = {ce2, cnt1, cnt2, tps0, tps1, tps2, itr0, itr1, itr2};
#pragma unroll
    for (int k = 0; k < 9; ++k) {
#pragma unroll
      for (int off = 32; off > 0; off >>= 1)
        v[k] += __shfl_down(v[k], off, 64);
    }
    if (lane == 0) {
      float c1 = v[1], c2 = v[2];
      float c0 = (float)HW_ - c1 - c2;
      float coef = (2.f * v[6] + 1.f) / (v[3] + c0 + 1.f)
                 + (2.f * v[7] + 1.f) / (v[4] + c1 + 1.f)
                 + (2.f * v[8] + 1.f) / (v[5] + c2 + 1.f);
      ceS[img] = v[0];
      coefS[img] = coef;
    }
  }
  __syncthreads();
  if (t == 0) {
    float cesum = 0.f, cf = 0.f;
#pragma unroll
    for (int i = 0; i < B_; ++i) { cesum += ceS[i]; cf += coefS[i]; }
    out[0] = cesum / ((float)B_ * (float)HW_) + 1.f - cf / (float)(B_ * C_);
  }
}

extern "C" void kernel_launch(void* const* d_in, const int* in_sizes, int n_in,
                              void* d_out, int out_size, void* d_ws, size_t ws_size,
                              hipStream_t stream) {
  const float* pred = (const float*)d_in[0];
  const int*   tgt  = (const int*)d_in[1];
  float*       out  = (float*)d_out;
  float*       ws   = (float*)d_ws;

  // Zero the arrival counter (workspace is poisoned by the harness each
  // iteration). 4-byte async memset is graph-capture-safe.
  hipMemsetAsync((void*)(ws + CNT_OFF_FLOATS), 0, sizeof(unsigned int), stream);
  dice_ce_fused<<<NBLOCKS, THREADS, 0, stream>>>(pred, tgt, ws, out);
}

// Round 2
// 112.093 us; speedup vs baseline: 1.4070x; 1.4070x over previous
//
#include <hip/hip_runtime.h>

// Problem constants (fixed by setup_inputs).
constexpr int B_   = 16;
constexpr int C_   = 3;
constexpr int HW_  = 512 * 512;          // 262144 pixels per image
constexpr int THREADS = 256;
constexpr int BLOCKS_PER_IMG = 128;      // power of 2 (mod via mask)
constexpr int NBLOCKS = B_ * BLOCKS_PER_IMG;             // 2048
constexpr int F4_PER_BLOCK = HW_ / 4 / BLOCKS_PER_IMG;   // 512 float4 per block
constexpr int ITERS = F4_PER_BLOCK / THREADS;            // 2 -> 8 pixels/thread

// CE fixed-point scale. Per-image max ce*2^20 ~= 262144*13*2^20 ~ 3.6e12 << 2^64.
constexpr float  CE_SCALE = 1048576.f;       // 2^20
constexpr double CE_INV_D = 1.0 / 1048576.0;

// Per-image accumulator. All cross-block communication is via device-scope
// atomics ONLY — no __threadfence (round-1 post-mortem: its buffer_wbl2 +
// buffer_inv per block thrashed every XCD L2 -> 10x slowdown).
// Counters (arrive / g_done) are MONOTONIC: each execution adds exactly 128
// per image / 16 global, so "last" is detected by mod-mask — no zeroing
// dispatch needed, and rocprof replays stay self-consistent.
struct __align__(64) ImgAcc {
  unsigned long long q[4];   // cnt1|cnt2<<32, tps0|tps1<<32, tps2|itr0<<32, itr1|itr2<<32
  unsigned long long ce;     // fixed-point 2^20
  unsigned arrive;           // monotonic, mod 128
  unsigned pad[5];
};

__device__ ImgAcc g_img[B_];     // zero-initialized at module load (.bss)
__device__ unsigned g_done;      // monotonic, mod 16

__global__ __launch_bounds__(THREADS) void dice_ce_fused(
    const float* __restrict__ pred, const int* __restrict__ tgt,
    float* __restrict__ out) {
  const int b = blockIdx.x / BLOCKS_PER_IMG;
  const int j = blockIdx.x % BLOCKS_PER_IMG;
  const int t = threadIdx.x;

  const float4* p0 = (const float4*)(pred + (size_t)b * C_ * HW_);
  const float4* p1 = (const float4*)(pred + (size_t)b * C_ * HW_ + HW_);
  const float4* p2 = (const float4*)(pred + (size_t)b * C_ * HW_ + 2 * HW_);
  const int4*   tg = (const int4*)(tgt + (size_t)b * HW_);

  // Issue ALL loads up front -> 8 outstanding vmem ops per wave.
  float4 A0[ITERS], A1[ITERS], A2[ITERS];
  int4   T[ITERS];
#pragma unroll
  for (int i = 0; i < ITERS; ++i) {
    const int idx = j * F4_PER_BLOCK + i * THREADS + t;
    A0[i] = p0[idx];
    A1[i] = p1[idx];
    A2[i] = p2[idx];
    T[i]  = tg[idx];
  }

  float ce = 0.f;
  int pkA = 0, pkB = 0, pkC = 0, pkD = 0;

#pragma unroll
  for (int i = 0; i < ITERS; ++i) {
    float x0s[4] = {A0[i].x, A0[i].y, A0[i].z, A0[i].w};
    float x1s[4] = {A1[i].x, A1[i].y, A1[i].z, A1[i].w};
    float x2s[4] = {A2[i].x, A2[i].y, A2[i].z, A2[i].w};
    int   tvs[4] = {T[i].x, T[i].y, T[i].z, T[i].w};
#pragma unroll
    for (int k = 0; k < 4; ++k) {
      float x0 = x0s[k], x1 = x1s[k], x2 = x2s[k];
      int tv = tvs[k];
      float m  = fmaxf(x0, fmaxf(x1, x2));
      float e0 = __expf(x0 - m), e1 = __expf(x1 - m), e2 = __expf(x2 - m);
      float s  = e0 + e1 + e2;
      float ls = __logf(s);
      float xt = (tv == 0) ? x0 : ((tv == 1) ? x1 : x2);
      ce += (m + ls) - xt;  // -= logp[target]; always >= 0
      // trunc(softmax prob) == 1 iff e_i carries the whole f32 sum (prob
      // rounds to exactly 1.0). Needs logit gap > ~16.6; never for N(0,1).
      int t0 = (e0 >= s) ? 1 : 0;
      int t1 = (e1 >= s) ? 1 : 0;
      int t2 = (e2 >= s) ? 1 : 0;
      pkA += ((tv == 1) ? 1 : 0) + ((tv == 2) ? (1 << 16) : 0);
      pkB += t0 + (t1 << 16);
      pkC += t2 + (((tv == 0) ? t0 : 0) << 16);
      pkD += ((tv == 1) ? t1 : 0) + (((tv == 2) ? t2 : 0) << 16);
    }
  }

  // Block reduction of 5 channels: wave shuffle then cross-wave LDS.
  int pks[4] = {pkA, pkB, pkC, pkD};
#pragma unroll
  for (int off = 32; off > 0; off >>= 1) {
    ce += __shfl_down(ce, off, 64);
#pragma unroll
    for (int k = 0; k < 4; ++k) pks[k] += __shfl_down(pks[k], off, 64);
  }

  __shared__ float ceR[THREADS / 64];
  __shared__ int   pkR[THREADS / 64][4];
  __shared__ int   tailFlag;
  const int wave = t >> 6, lane = t & 63;
  if (lane == 0) {
    ceR[wave] = ce;
#pragma unroll
    for (int k = 0; k < 4; ++k) pkR[wave][k] = pks[k];
  }
  __syncthreads();
  if (t == 0) {
#pragma unroll
    for (int w = 1; w < THREADS / 64; ++w) {
      ce += ceR[w];
#pragma unroll
      for (int k = 0; k < 4; ++k) pks[k] += pkR[w][k];
    }
    // Widen packed u16 pairs to u32 pairs in u64 (no carry: per-image sums
    // <= 262144 < 2^32). 4 u64 adds + 1 ce add + 1 arrival = 6 atomics/block.
    ImgAcc* a = &g_img[b];
    atomicAdd(&a->q[0], (unsigned long long)((unsigned)pks[0] & 0xffffu) |
                        ((unsigned long long)((unsigned)pks[0] >> 16) << 32));
    atomicAdd(&a->q[1], (unsigned long long)((unsigned)pks[1] & 0xffffu) |
                        ((unsigned long long)((unsigned)pks[1] >> 16) << 32));
    atomicAdd(&a->q[2], (unsigned long long)((unsigned)pks[2] & 0xffffu) |
                        ((unsigned long long)((unsigned)pks[2] >> 16) << 32));
    atomicAdd(&a->q[3], (unsigned long long)((unsigned)pks[3] & 0xffffu) |
                        ((unsigned long long)((unsigned)pks[3] >> 16) << 32));
    atomicAdd(&a->ce, (unsigned long long)llrintf(ce * CE_SCALE));
    // Release WITHOUT cache flush: atomics are performed at the coherence
    // point; waiting for completion (vmcnt) orders them before the arrival.
    asm volatile("s_waitcnt vmcnt(0)" ::: "memory");
    int tf = 0;
    unsigned old = atomicAdd(&a->arrive, 1u);
    if ((old & (unsigned)(BLOCKS_PER_IMG - 1)) == (unsigned)(BLOCKS_PER_IMG - 1)) {
      // This block completed its image; bump the image-done counter.
      unsigned od = atomicAdd(&g_done, 1u);
      tf = ((od & (unsigned)(B_ - 1)) == (unsigned)(B_ - 1)) ? 1 : 0;
    }
    tailFlag = tf;
  }
  __syncthreads();
  if (tailFlag == 0) return;

  // ---- Tail: the block that observed the 16th image-completion. ----
  // All other blocks' adds are globally performed (each arrival/done
  // increment was preceded by vmcnt(0) on that block's value-adds).
  __shared__ float coefS[B_];
  __shared__ unsigned long long ceQ[B_];
  if (t < B_) {
    ImgAcc* a = &g_img[t];
    unsigned long long q0 = __hip_atomic_load(&a->q[0], __ATOMIC_RELAXED, __HIP_MEMORY_SCOPE_AGENT);
    unsigned long long q1 = __hip_atomic_load(&a->q[1], __ATOMIC_RELAXED, __HIP_MEMORY_SCOPE_AGENT);
    unsigned long long q2 = __hip_atomic_load(&a->q[2], __ATOMIC_RELAXED, __HIP_MEMORY_SCOPE_AGENT);
    unsigned long long q3 = __hip_atomic_load(&a->q[3], __ATOMIC_RELAXED, __HIP_MEMORY_SCOPE_AGENT);
    unsigned long long cq = __hip_atomic_load(&a->ce,   __ATOMIC_RELAXED, __HIP_MEMORY_SCOPE_AGENT);
    // Self-clean for the next (stream-serialized) execution. Same-address
    // program order per thread guarantees load-before-store.
    __hip_atomic_store(&a->q[0], 0ull, __ATOMIC_RELAXED, __HIP_MEMORY_SCOPE_AGENT);
    __hip_atomic_store(&a->q[1], 0ull, __ATOMIC_RELAXED, __HIP_MEMORY_SCOPE_AGENT);
    __hip_atomic_store(&a->q[2], 0ull, __ATOMIC_RELAXED, __HIP_MEMORY_SCOPE_AGENT);
    __hip_atomic_store(&a->q[3], 0ull, __ATOMIC_RELAXED, __HIP_MEMORY_SCOPE_AGENT);
    __hip_atomic_store(&a->ce,   0ull, __ATOMIC_RELAXED, __HIP_MEMORY_SCOPE_AGENT);
    // Counts <= 4.19e6 < 2^24: float conversion exact -> coef arithmetic is
    // bitwise-identical to the round-0 final kernel.
    float cnt1 = (float)(unsigned)(q0 & 0xffffffffull);
    float cnt2 = (float)(unsigned)(q0 >> 32);
    float tps0 = (float)(unsigned)(q1 & 0xffffffffull);
    float tps1 = (float)(unsigned)(q1 >> 32);
    float tps2 = (float)(unsigned)(q2 & 0xffffffffull);
    float itr0 = (float)(unsigned)(q2 >> 32);
    float itr1 = (float)(unsigned)(q3 & 0xffffffffull);
    float itr2 = (float)(unsigned)(q3 >> 32);
    float c0 = (float)HW_ - cnt1 - cnt2;
    float coef = (2.f * itr0 + 1.f) / (tps0 + c0 + 1.f)
               + (2.f * itr1 + 1.f) / (tps1 + cnt1 + 1.f)
               + (2.f * itr2 + 1.f) / (tps2 + cnt2 + 1.f);
    coefS[t] = coef;
    ceQ[t] = cq;
  }
  __syncthreads();
  if (t == 0) {
    unsigned long long tot = 0;
    float cf = 0.f;
#pragma unroll
    for (int i = 0; i < B_; ++i) { tot += ceQ[i]; cf += coefS[i]; }
    float cesum = (float)((double)tot * CE_INV_D);  // exact u64 sum, one rounding
    out[0] = cesum / ((float)B_ * (float)HW_) + 1.f - cf / (float)(B_ * C_);
  }
}

extern "C" void kernel_launch(void* const* d_in, const int* in_sizes, int n_in,
                              void* d_out, int out_size, void* d_ws, size_t ws_size,
                              hipStream_t stream) {
  const float* pred = (const float*)d_in[0];
  const int*   tgt  = (const int*)d_in[1];
  float*       out  = (float*)d_out;
  (void)d_ws; (void)ws_size;

  // Single dispatch: no workspace, no memset (monotonic __device__ counters).
  dice_ce_fused<<<NBLOCKS, THREADS, 0, stream>>>(pred, tgt, out);
}

// Round 3
// 97.233 us; speedup vs baseline: 1.6221x; 1.1528x over previous
//
#include <hip/hip_runtime.h>

// Problem constants (fixed by setup_inputs).
constexpr int B_   = 16;
constexpr int C_   = 3;
constexpr int HW_  = 512 * 512;          // 262144 pixels per image
constexpr int THREADS = 256;
constexpr int BLOCKS_PER_IMG = 128;
constexpr int NBLOCKS = B_ * BLOCKS_PER_IMG;             // 2048
constexpr int F4_PER_BLOCK = HW_ / 4 / BLOCKS_PER_IMG;   // 512 float4 per block
constexpr int ITERS = F4_PER_BLOCK / THREADS;            // 2 -> 8 pixels/thread
constexpr int REC = 8;   // floats per block record (2 x float4)

// Record layout per block (8 floats):
//  [0] ce sum (float)
//  [1] cnt1 | cnt2<<16        (bit-cast u32; cnt0 derived at the end)
//  [2] tps0 | tps1<<16
//  [3] tps2 | itr0<<16
//  [4] itr1 | itr2<<16
//  [5..7] pad
// Per-block packed fields are <= 2048 (pixels/block) < 2^16: no overflow.
//
// NOTE (rounds 1-2 post-mortem): keep this as TWO dispatches. Fusing the
// final reduction into the bulk kernel requires device-scope visibility of
// per-block results; on gfx950 both mechanisms tried cost more than the
// ~3 us second dispatch:
//  - __threadfence() release/acquire => buffer_wbl2 + buffer_inv per block,
//    thrashes every XCD's L2 -> bulk kernel 10x slower (round 1, +61 us).
//  - device-scope atomicAdd accumulators packed in one 64B line => ~768
//    serialized line RMWs per image at the coherence point (round 2, +15 us).

__global__ __launch_bounds__(THREADS) void dice_ce_partial(
    const float* __restrict__ pred, const int* __restrict__ tgt,
    float* __restrict__ ws) {
  const int b = blockIdx.x / BLOCKS_PER_IMG;
  const int j = blockIdx.x % BLOCKS_PER_IMG;
  const int t = threadIdx.x;

  const float4* p0 = (const float4*)(pred + (size_t)b * C_ * HW_);
  const float4* p1 = (const float4*)(pred + (size_t)b * C_ * HW_ + HW_);
  const float4* p2 = (const float4*)(pred + (size_t)b * C_ * HW_ + 2 * HW_);
  const int4*   tg = (const int4*)(tgt + (size_t)b * HW_);

  // Issue ALL loads up front -> 8 outstanding vmem ops per wave.
  float4 A0[ITERS], A1[ITERS], A2[ITERS];
  int4   T[ITERS];
#pragma unroll
  for (int i = 0; i < ITERS; ++i) {
    const int idx = j * F4_PER_BLOCK + i * THREADS + t;
    A0[i] = p0[idx];
    A1[i] = p1[idx];
    A2[i] = p2[idx];
    T[i]  = tg[idx];
  }

  float ce = 0.f;
  int pkA = 0, pkB = 0, pkC = 0, pkD = 0;

#pragma unroll
  for (int i = 0; i < ITERS; ++i) {
    float x0s[4] = {A0[i].x, A0[i].y, A0[i].z, A0[i].w};
    float x1s[4] = {A1[i].x, A1[i].y, A1[i].z, A1[i].w};
    float x2s[4] = {A2[i].x, A2[i].y, A2[i].z, A2[i].w};
    int   tvs[4] = {T[i].x, T[i].y, T[i].z, T[i].w};
#pragma unroll
    for (int k = 0; k < 4; ++k) {
      float x0 = x0s[k], x1 = x1s[k], x2 = x2s[k];
      int tv = tvs[k];
      float m  = fmaxf(x0, fmaxf(x1, x2));
      float e0 = __expf(x0 - m), e1 = __expf(x1 - m), e2 = __expf(x2 - m);
      float s  = e0 + e1 + e2;
      float ls = __logf(s);
      float xt = (tv == 0) ? x0 : ((tv == 1) ? x1 : x2);
      ce += (m + ls) - xt;  // -= logp[target]
      // trunc(softmax prob) == 1 iff e_i carries the whole f32 sum (prob
      // rounds to exactly 1.0). Needs logit gap > ~16.6; never for N(0,1).
      int t0 = (e0 >= s) ? 1 : 0;
      int t1 = (e1 >= s) ? 1 : 0;
      int t2 = (e2 >= s) ? 1 : 0;
      pkA += ((tv == 1) ? 1 : 0) + ((tv == 2) ? (1 << 16) : 0);
      pkB += t0 + (t1 << 16);
      pkC += t2 + (((tv == 0) ? t0 : 0) << 16);
      pkD += ((tv == 1) ? t1 : 0) + (((tv == 2) ? t2 : 0) << 16);
    }
  }

  // Block reduction of 5 channels: wave shuffle then cross-wave LDS.
  int pks[4] = {pkA, pkB, pkC, pkD};
#pragma unroll
  for (int off = 32; off > 0; off >>= 1) {
    ce += __shfl_down(ce, off, 64);
#pragma unroll
    for (int k = 0; k < 4; ++k) pks[k] += __shfl_down(pks[k], off, 64);
  }

  __shared__ float ceR[THREADS / 64];
  __shared__ int   pkR[THREADS / 64][4];
  const int wave = t >> 6, lane = t & 63;
  if (lane == 0) {
    ceR[wave] = ce;
#pragma unroll
    for (int k = 0; k < 4; ++k) pkR[wave][k] = pks[k];
  }
  __syncthreads();
  if (t == 0) {
#pragma unroll
    for (int w = 1; w < THREADS / 64; ++w) {
      ce += ceR[w];
#pragma unroll
      for (int k = 0; k < 4; ++k) pks[k] += pkR[w][k];
    }
    float4* rec = (float4*)(ws + (size_t)blockIdx.x * REC);
    rec[0] = make_float4(ce, __int_as_float(pks[0]), __int_as_float(pks[1]),
                         __int_as_float(pks[2]));
    rec[1] = make_float4(__int_as_float(pks[3]), 0.f, 0.f, 0.f);
  }
}

// One wave per image reduces its 128 block records (2 per lane).
__global__ __launch_bounds__(1024) void dice_ce_final(
    const float* __restrict__ ws, float* __restrict__ out) {
  const int t = threadIdx.x;        // 0..1023
  const int img = t >> 6;           // one wave per image
  const int lane = t & 63;

  float ce = 0.f;
  float cnt1 = 0.f, cnt2 = 0.f;
  float tps0 = 0.f, tps1 = 0.f, tps2 = 0.f;
  float itr0 = 0.f, itr1 = 0.f, itr2 = 0.f;
#pragma unroll
  for (int r = 0; r < 2; ++r) {
    const int idx = img * BLOCKS_PER_IMG + r * 64 + lane;
    const float4* rec = (const float4*)(ws + (size_t)idx * REC);
    float4 r0 = rec[0], r1 = rec[1];
    ce += r0.x;
    int pA = __float_as_int(r0.y), pB = __float_as_int(r0.z);
    int pC = __float_as_int(r0.w), pD = __float_as_int(r1.x);
    cnt1 += (float)(pA & 0xffff); cnt2 += (float)(pA >> 16);
    tps0 += (float)(pB & 0xffff); tps1 += (float)(pB >> 16);
    tps2 += (float)(pC & 0xffff); itr0 += (float)(pC >> 16);
    itr1 += (float)(pD & 0xffff); itr2 += (float)(pD >> 16);
  }
  float v[9] = {ce, cnt1, cnt2, tps0, tps1, tps2, itr0, itr1, itr2};
#pragma unroll
  for (int k = 0; k < 9; ++k) {
#pragma unroll
    for (int off = 32; off > 0; off >>= 1) v[k] += __shfl_down(v[k], off, 64);
  }

  __shared__ float ceS[16];
  __shared__ float coefS[16];
  if (lane == 0) {
    float c1 = v[1], c2 = v[2];
    float c0 = (float)HW_ - c1 - c2;
    float coef = (2.f * v[6] + 1.f) / (v[3] + c0 + 1.f)
               + (2.f * v[7] + 1.f) / (v[4] + c1 + 1.f)
               + (2.f * v[8] + 1.f) / (v[5] + c2 + 1.f);
    ceS[img] = v[0];
    coefS[img] = coef;
  }
  __syncthreads();
  if (t == 0) {
    float cesum = 0.f, cf = 0.f;
#pragma unroll
    for (int i = 0; i < 16; ++i) { cesum += ceS[i]; cf += coefS[i]; }
    out[0] = cesum / ((float)B_ * (float)HW_) + 1.f - cf / (float)(B_ * C_);
  }
}

extern "C" void kernel_launch(void* const* d_in, const int* in_sizes, int n_in,
                              void* d_out, int out_size, void* d_ws, size_t ws_size,
                              hipStream_t stream) {
  const float* pred = (const float*)d_in[0];
  const int*   tgt  = (const int*)d_in[1];
  float*       out  = (float*)d_out;
  float*       ws   = (float*)d_ws;

  dice_ce_partial<<<NBLOCKS, THREADS, 0, stream>>>(pred, tgt, ws);
  dice_ce_final<<<1, 1024, 0, stream>>>(ws, out);
}